// Round 5
// baseline (915.848 us; speedup 1.0000x reference)
//
#include <hip/hip_runtime.h>

typedef unsigned short u16;
typedef float f32x4 __attribute__((ext_vector_type(4)));
typedef __bf16 bf16x8 __attribute__((ext_vector_type(8)));

#define AS1(p) ((const __attribute__((address_space(1))) void*)(p))
#define AS3(p) ((__attribute__((address_space(3))) void*)(p))

#define LOG2E 1.44269504088896f

__device__ __forceinline__ u16 f2bf(float f) {
    return __builtin_bit_cast(u16, (__bf16)f);   // RTNE, hw cvt on gfx950
}
__device__ __forceinline__ float bf2f(u16 u) {
    return __builtin_bit_cast(float, (unsigned)u << 16);
}

// ---------------- fused cast f32 -> bf16 over 5 segments ----------------
__global__ __launch_bounds__(256) void cast_all_bf16(
    const float* __restrict__ s0, const float* __restrict__ s1,
    const float* __restrict__ s2, const float* __restrict__ s3,
    const float* __restrict__ s4,
    u16* __restrict__ d0, u16* __restrict__ d1, u16* __restrict__ d2,
    u16* __restrict__ d3, u16* __restrict__ d4)
{
    const int n0 = 2097152;
    const int e1 = n0 + 786432;
    const int e2 = e1 + 262144;
    const int e3 = e2 + 1048576;
    const int e4 = e3 + 1048576;
    int stride = gridDim.x * blockDim.x;
    for (int i = blockIdx.x * blockDim.x + threadIdx.x; i < e4; i += stride) {
        const float* src; u16* dst; int li;
        if (i < n0)      { src = s0; dst = d0; li = i; }
        else if (i < e1) { src = s1; dst = d1; li = i - n0; }
        else if (i < e2) { src = s2; dst = d2; li = i - e1; }
        else if (i < e3) { src = s3; dst = d3; li = i - e2; }
        else             { src = s4; dst = d4; li = i - e3; }
        float4 v = ((const float4*)src)[li];
        ushort4 o;
        o.x = f2bf(v.x); o.y = f2bf(v.y); o.z = f2bf(v.z); o.w = f2bf(v.w);
        ((ushort4*)dst)[li] = o;
    }
}

// ---------------- 128x128 GEMM, 2-phase double-buffered ------------------
// The workhorse for ALL GEMMs (R13: 2-phase beat 1-phase; R15/R16: beats
// the 256^2 gemm8p at every shape tried — 5 blocks/CU TLP wins).
// MODE 0: QKV scatter.  MODE 1: bf16 out = acc+bias+res_f32.
// MODE 2: bf16 out = relu(acc+bias).  MODE 3: bf16 out = acc+bias+res_bf16.
template <int MODE>
__global__ __launch_bounds__(256)
void gemm_bt(const u16* __restrict__ A, const u16* __restrict__ Bt,
             const float* __restrict__ bias, const float* __restrict__ res,
             const u16* __restrict__ resb,
             void* __restrict__ outp, int M, int N, int K,
             u16* __restrict__ qb, u16* __restrict__ kb, u16* __restrict__ vT)
{
    __shared__ u16 As[2][128 * 32];
    __shared__ u16 Bs[2][128 * 32];
    const int tid = threadIdx.x;
    const int m0 = blockIdx.x * 128, n0 = blockIdx.y * 128;
    const int wid = tid >> 6, lane = tid & 63;
    const int wm = (wid >> 1) * 64, wn = (wid & 1) * 64;
    const int lr = lane & 15, lg = lane >> 4;
    f32x4 acc[4][4] = {};

    const int row0 = tid >> 2, cc0 = (tid & 3) * 8;
    const int row1 = row0 + 64;
    const int lo0 = (tid & ~63) * 16;
    const int lo1 = 256 * 16 + lo0;

#define GSTG(buf, k0_) do {                                                    \
    __builtin_amdgcn_global_load_lds(                                          \
        AS1(A + (size_t)(m0 + row0) * K + (k0_) + cc0),                        \
        AS3((char*)As[buf] + lo0), 16, 0, 0);                                  \
    __builtin_amdgcn_global_load_lds(                                          \
        AS1(A + (size_t)(m0 + row1) * K + (k0_) + cc0),                        \
        AS3((char*)As[buf] + lo1), 16, 0, 0);                                  \
    __builtin_amdgcn_global_load_lds(                                          \
        AS1(Bt + (size_t)(n0 + row0) * K + (k0_) + cc0),                       \
        AS3((char*)Bs[buf] + lo0), 16, 0, 0);                                  \
    __builtin_amdgcn_global_load_lds(                                          \
        AS1(Bt + (size_t)(n0 + row1) * K + (k0_) + cc0),                       \
        AS3((char*)Bs[buf] + lo1), 16, 0, 0);                                  \
} while (0)

    GSTG(0, 0);
    __syncthreads();

    const int NT = K >> 5;
    for (int t = 0; t < NT; ++t) {
        const int cur = t & 1;
        if (t + 1 < NT) GSTG(cur ^ 1, (t + 1) << 5);
        bf16x8 af[4];
#pragma unroll
        for (int i = 0; i < 4; ++i)
            af[i] = *(const bf16x8*)&As[cur][(wm + i * 16 + lr) * 32 + lg * 8];
#pragma unroll
        for (int j = 0; j < 4; ++j) {
            bf16x8 bf = *(const bf16x8*)&Bs[cur][(wn + j * 16 + lr) * 32 + lg * 8];
#pragma unroll
            for (int i = 0; i < 4; ++i)
                acc[i][j] = __builtin_amdgcn_mfma_f32_16x16x32_bf16(af[i], bf, acc[i][j], 0, 0, 0);
        }
        __syncthreads();
    }
#undef GSTG

#pragma unroll
    for (int i = 0; i < 4; ++i) {
#pragma unroll
        for (int j = 0; j < 4; ++j) {
            int col = n0 + wn + j * 16 + lr;
            float bv = bias[col];
#pragma unroll
            for (int r = 0; r < 4; ++r) {
                int mr = m0 + wm + i * 16 + lg * 4 + r;
                float v = acc[i][j][r] + bv;
                if (MODE == 0) {
                    int b_ = mr >> 11, s_ = mr & 2047;
                    int h_ = col / 192, rr = col - h_ * 192;
                    int bh = b_ * 16 + h_;
                    if (rr < 64)
                        qb[((size_t)bh * 2048 + s_) * 64 + rr] = f2bf(v * (0.125f * LOG2E));
                    else if (rr < 128)
                        kb[((size_t)bh * 2048 + s_) * 64 + (rr - 64)] = f2bf(v);
                    else
                        vT[((size_t)bh * 64 + (rr - 128)) * 2048 + s_] = f2bf(v);
                } else if (MODE == 1) {
                    ((u16*)outp)[(size_t)mr * N + col] = f2bf(v + res[(size_t)mr * N + col]);
                } else if (MODE == 3) {
                    ((u16*)outp)[(size_t)mr * N + col] = f2bf(v + bf2f(resb[(size_t)mr * N + col]));
                } else {
                    ((u16*)outp)[(size_t)mr * N + col] = f2bf(fmaxf(v, 0.0f));
                }
            }
        }
    }
}

// ---------------- flash attention forward (R21) ---------------------------
// R21 = R20 per-wave code (mask prefetch + setprio, 485.8us total) with
// K/V double-buffer replaced by SINGLE LDS buffer + register staging
// (T14 issue-early/write-late): global_load_dwordx4 K/V[it+1] -> 8 VGPR
// at iter top (same pre-swizzled addresses -> identical LDS image),
// consume whole iteration as latency cover, then read-barrier ->
// ds_write_b128 -> write-barrier. LDS 50176 -> 33792 B: 4 blocks/CU
// (wave-cap) vs 3, grid = exactly 4/CU -> eliminates the straggler round
// that made avg occupancy 40% (T_tail ~= T_main, ~half of wall time for
// 25% of work). Cost: +1 barrier + 2 ds_write_b128/iter, +8 VGPR.
// lb(512,8) keeps VGPR<=64 (R18/R19: crossing 64 spills; WRITE_SIZE
// inflation over ~16.4MB = spill = revert trigger).
__global__ __launch_bounds__(512, 8)
void attn_fwd(const u16* __restrict__ qb, const u16* __restrict__ kb,
              const u16* __restrict__ vT, const float* __restrict__ mask,
              u16* __restrict__ ctx)
{
    __shared__ u16 Ks[64 * 64];
    __shared__ u16 Vs[64 * 64];
    __shared__ u16 Plds[8 * 16 * 68];
    const int tid = threadIdx.x;
    const int wid = tid >> 6, lane = tid & 63;
    const int lr = lane & 15, lg = lane >> 4;
    const int id = blockIdx.x;
    const int job = (id & 7) * 128 + (id >> 3);
    const int qt = job & 15, h = (job >> 4) & 15, b = job >> 8;
    const int bh = b * 16 + h;
    const int q0 = qt * 128 + wid * 16;
    u16* pl = &Plds[wid * 16 * 68];

    const size_t kbase = (size_t)bh * 2048 * 64;
    const size_t vbase = (size_t)bh * 64 * 2048;

    const int cr = tid >> 3, ck = tid & 7;
    const int sk = ck ^ (cr & 7);
    const int lob = tid * 16;   // this thread's 16B slot in Ks/Vs (byte offset)

    bf16x8 qf[2];
#pragma unroll
    for (int ks = 0; ks < 2; ++ks)
        qf[ks] = *(const bf16x8*)(qb + ((size_t)bh * 2048 + q0 + lr) * 64 + ks * 32 + lg * 8);

    f32x4 octx[4] = {};
    float lsum[4] = {};
    const size_t mbase = ((size_t)b * 2048 + q0) * 2048;

    // prologue: stage tile 0 through regs (same pre-swizzled source addrs
    // as the old global_load_lds path -> identical LDS image)
    {
        uint4 k0 = *(const uint4*)(kb + kbase + (size_t)cr * 64 + sk * 8);
        uint4 v0 = *(const uint4*)(vT + vbase + (size_t)cr * 2048 + sk * 8);
        *(uint4*)((char*)Ks + lob) = k0;
        *(uint4*)((char*)Vs + lob) = v0;
    }
    __syncthreads();

    // mask prefetch for it=0 (loop-carried mv; refilled before each PV)
    float mv[4][4];
#pragma unroll
    for (int j = 0; j < 4; ++j)
#pragma unroll
        for (int r = 0; r < 4; ++r)
            mv[j][r] = mask[mbase + (size_t)(lg * 4 + r) * 2048 + j * 16 + lr];

    for (int it = 0; it < 32; ++it) {
        const int t0 = it * 64;

        // issue next-tile loads into regs NOW; vmcnt-waited just before the
        // ds_write at iteration bottom -> full iteration of latency cover
        uint4 kN, vN;
        if (it < 31) {
            const int tn = t0 + 64;
            kN = *(const uint4*)(kb + kbase + (size_t)(tn + cr) * 64 + sk * 8);
            vN = *(const uint4*)(vT + vbase + (size_t)cr * 2048 + tn + sk * 8);
        }

        f32x4 sc[4];
        __builtin_amdgcn_s_setprio(1);
#pragma unroll
        for (int j = 0; j < 4; ++j) {
            f32x4 s = {0.f, 0.f, 0.f, 0.f};
#pragma unroll
            for (int ks = 0; ks < 2; ++ks) {
                const int R = j * 16 + lr;
                const int off = R * 128 + ((ks * 64 + lg * 16) ^ ((R & 7) * 16));
                bf16x8 kf = *(const bf16x8*)((const char*)Ks + off);
                s = __builtin_amdgcn_mfma_f32_16x16x32_bf16(qf[ks], kf, s, 0, 0, 0);
            }
            sc[j] = s;
        }
        __builtin_amdgcn_s_setprio(0);

#pragma unroll
        for (int j = 0; j < 4; ++j) {
#pragma unroll
            for (int r = 0; r < 4; ++r) {
                float p = __builtin_amdgcn_exp2f(fmaf(mv[j][r], LOG2E, sc[j][r]) - 24.0f);
                sc[j][r] = p;
                lsum[r] += p;
            }
        }
#pragma unroll
        for (int j = 0; j < 4; ++j)
#pragma unroll
            for (int r = 0; r < 4; ++r)
                pl[(lg * 4 + r) * 68 + j * 16 + lr] = f2bf(sc[j][r]);

        // mask prefetch for it+1: covered by PV + barriers + QK before use
        if (it < 31) {
            const int tn = t0 + 64;
#pragma unroll
            for (int j = 0; j < 4; ++j)
#pragma unroll
                for (int r = 0; r < 4; ++r)
                    mv[j][r] = mask[mbase + (size_t)(lg * 4 + r) * 2048 + tn + j * 16 + lr];
        }

        __builtin_amdgcn_s_setprio(1);
#pragma unroll
        for (int ks = 0; ks < 2; ++ks) {
            bf16x8 pa = *(const bf16x8*)&pl[lr * 68 + ks * 32 + lg * 8];
#pragma unroll
            for (int dj = 0; dj < 4; ++dj) {
                const int R = dj * 16 + lr;
                const int off = R * 128 + ((ks * 64 + lg * 16) ^ ((R & 7) * 16));
                bf16x8 vf = *(const bf16x8*)((const char*)Vs + off);
                octx[dj] = __builtin_amdgcn_mfma_f32_16x16x32_bf16(pa, vf, octx[dj], 0, 0, 0);
            }
        }
        __builtin_amdgcn_s_setprio(0);

        __syncthreads();              // all waves done READING Ks/Vs tile it
        if (it < 31) {
            *(uint4*)((char*)Ks + lob) = kN;   // compiler inserts vmcnt wait
            *(uint4*)((char*)Vs + lob) = vN;
        }
        __syncthreads();              // tile it+1 visible
    }

#pragma unroll
    for (int r = 0; r < 4; ++r)
#pragma unroll
        for (int o = 1; o < 16; o <<= 1) lsum[r] += __shfl_xor(lsum[r], o);

#pragma unroll
    for (int dj = 0; dj < 4; ++dj)
#pragma unroll
        for (int r = 0; r < 4; ++r) {
            float o = octx[dj][r] / lsum[r];
            ctx[((size_t)b * 2048 + q0 + lg * 4 + r) * 1024 + h * 64 + dj * 16 + lr] = f2bf(o);
        }
}

// ---------------- LayerNorm (row = 1024), bf16 in, eps added to std -------
__global__ __launch_bounds__(256)
void ln_fwd(const u16* __restrict__ in, const float* __restrict__ gamma,
            const float* __restrict__ beta, float* __restrict__ out32,
            u16* __restrict__ outbf)
{
    __shared__ float red[4], red2[4];
    const int tid = threadIdx.x;
    const size_t row = blockIdx.x;
    ushort4 raw = ((const ushort4*)(in + row * 1024))[tid];
    float vx = bf2f(raw.x), vy = bf2f(raw.y), vz = bf2f(raw.z), vw = bf2f(raw.w);
    float s  = vx + vy + vz + vw;
    float s2 = vx * vx + vy * vy + vz * vz + vw * vw;
#pragma unroll
    for (int o = 32; o; o >>= 1) {
        s  += __shfl_xor(s, o);
        s2 += __shfl_xor(s2, o);
    }
    if ((tid & 63) == 0) { red[tid >> 6] = s; red2[tid >> 6] = s2; }
    __syncthreads();
    float mean = (red[0] + red[1] + red[2] + red[3]) * (1.0f / 1024.0f);
    float ex2  = (red2[0] + red2[1] + red2[2] + red2[3]) * (1.0f / 1024.0f);
    float var  = ex2 - mean * mean;
    float inv = 1.0f / (sqrtf(var) + 1e-6f);
    float dx = vx - mean, dy = vy - mean, dz = vz - mean, dw = vw - mean;
    float4 g = ((const float4*)gamma)[tid];
    float4 bb = ((const float4*)beta)[tid];
    float4 o;
    o.x = g.x * dx * inv + bb.x;
    o.y = g.y * dy * inv + bb.y;
    o.z = g.z * dz * inv + bb.z;
    o.w = g.w * dw * inv + bb.w;
    if (out32) ((float4*)(out32 + row * 1024))[tid] = o;
    if (outbf) {
        ushort4 ob;
        ob.x = f2bf(o.x); ob.y = f2bf(o.y); ob.z = f2bf(o.z); ob.w = f2bf(o.w);
        ((ushort4*)(outbf + row * 1024))[tid] = ob;
    }
}

extern "C" void kernel_launch(void* const* d_in, const int* in_sizes, int n_in,
                              void* d_out, int out_size, void* d_ws, size_t ws_size,
                              hipStream_t stream)
{
    (void)in_sizes; (void)n_in; (void)out_size; (void)ws_size;
    const float* x    = (const float*)d_in[0];
    const float* mask = (const float*)d_in[1];
    const float* Wqkv = (const float*)d_in[2];
    const float* bqkv = (const float*)d_in[3];
    const float* Wo   = (const float*)d_in[4];
    const float* bo   = (const float*)d_in[5];
    const float* W1   = (const float*)d_in[6];
    const float* b1   = (const float*)d_in[7];
    const float* W2   = (const float*)d_in[8];
    const float* b2   = (const float*)d_in[9];
    const float* g1   = (const float*)d_in[10];
    const float* be1  = (const float*)d_in[11];
    const float* g2   = (const float*)d_in[12];
    const float* be2  = (const float*)d_in[13];

    char* w = (char*)d_ws;
    u16* x_bf    = (u16*)w;  w += (size_t)8192 * 1024 * 2;   // kept live (Wo residual)
    u16* Wqkv_bf = (u16*)w;  w += (size_t)3072 * 1024 * 2;
    u16* Wo_bf   = (u16*)w;  w += (size_t)1024 * 1024 * 2;
    u16* W1_bf   = (u16*)w;  w += (size_t)4096 * 1024 * 2;
    u16* W2_bf   = (u16*)w;  w += (size_t)1024 * 4096 * 2;
    u16* qbuf    = (u16*)w;  w += (size_t)8192 * 1024 * 2;
    u16* kbuf    = (u16*)w;  w += (size_t)8192 * 1024 * 2;
    u16* vTbuf   = (u16*)w;  w += (size_t)8192 * 1024 * 2;
    u16* ctxbuf  = (u16*)w;  w += (size_t)8192 * 1024 * 2;
    u16* hb_wo   = (u16*)w;  w += (size_t)8192 * 1024 * 2;   // Wo out -> ln1 in
    u16* hbf     = (u16*)w;  w += (size_t)8192 * 1024 * 2;   // ln1 out: W1 A + W2 residual
    u16* hb_w2   = (u16*)w;  w += (size_t)8192 * 1024 * 2;   // W2 out -> ln2 in
    u16* ff1     = (u16*)w;  w += (size_t)8192 * 4096 * 2;

    cast_all_bf16<<<2048, 256, 0, stream>>>(x, Wqkv, Wo, W1, W2,
                                            x_bf, Wqkv_bf, Wo_bf, W1_bf, W2_bf);

    gemm_bt<0><<<dim3(64, 24), 256, 0, stream>>>(x_bf, Wqkv_bf, bqkv, nullptr, nullptr, nullptr,
                                                 8192, 3072, 1024, qbuf, kbuf, vTbuf);
    attn_fwd<<<1024, 512, 0, stream>>>(qbuf, kbuf, vTbuf, mask, ctxbuf);
    gemm_bt<3><<<dim3(64, 8), 256, 0, stream>>>(ctxbuf, Wo_bf, bo, nullptr, x_bf, hb_wo,
                                                8192, 1024, 1024, nullptr, nullptr, nullptr);
    ln_fwd<<<8192, 256, 0, stream>>>(hb_wo, g1, be1, nullptr, hbf);
    gemm_bt<2><<<dim3(64, 32), 256, 0, stream>>>(hbf, W1_bf, b1, nullptr, nullptr, ff1,
                                                 8192, 4096, 1024, nullptr, nullptr, nullptr);
    gemm_bt<3><<<dim3(64, 8), 256, 0, stream>>>(ff1, W2_bf, b2, nullptr, hbf, hb_w2,
                                                8192, 1024, 4096, nullptr, nullptr, nullptr);
    ln_fwd<<<8192, 256, 0, stream>>>(hb_w2, g2, be2, (float*)d_out, nullptr);
}

// Round 6
// 490.219 us; speedup vs baseline: 1.8682x; 1.8682x over previous
//
#include <hip/hip_runtime.h>

typedef unsigned short u16;
typedef float f32x4 __attribute__((ext_vector_type(4)));
typedef __bf16 bf16x8 __attribute__((ext_vector_type(8)));

#define AS1(p) ((const __attribute__((address_space(1))) void*)(p))
#define AS3(p) ((__attribute__((address_space(3))) void*)(p))

#define LOG2E 1.44269504088896f

__device__ __forceinline__ u16 f2bf(float f) {
    return __builtin_bit_cast(u16, (__bf16)f);   // RTNE, hw cvt on gfx950
}
__device__ __forceinline__ float bf2f(u16 u) {
    return __builtin_bit_cast(float, (unsigned)u << 16);
}

// ---------------- fused cast f32 -> bf16 over 5 segments ----------------
__global__ __launch_bounds__(256) void cast_all_bf16(
    const float* __restrict__ s0, const float* __restrict__ s1,
    const float* __restrict__ s2, const float* __restrict__ s3,
    const float* __restrict__ s4,
    u16* __restrict__ d0, u16* __restrict__ d1, u16* __restrict__ d2,
    u16* __restrict__ d3, u16* __restrict__ d4)
{
    const int n0 = 2097152;
    const int e1 = n0 + 786432;
    const int e2 = e1 + 262144;
    const int e3 = e2 + 1048576;
    const int e4 = e3 + 1048576;
    int stride = gridDim.x * blockDim.x;
    for (int i = blockIdx.x * blockDim.x + threadIdx.x; i < e4; i += stride) {
        const float* src; u16* dst; int li;
        if (i < n0)      { src = s0; dst = d0; li = i; }
        else if (i < e1) { src = s1; dst = d1; li = i - n0; }
        else if (i < e2) { src = s2; dst = d2; li = i - e1; }
        else if (i < e3) { src = s3; dst = d3; li = i - e2; }
        else             { src = s4; dst = d4; li = i - e3; }
        float4 v = ((const float4*)src)[li];
        ushort4 o;
        o.x = f2bf(v.x); o.y = f2bf(v.y); o.z = f2bf(v.z); o.w = f2bf(v.w);
        ((ushort4*)dst)[li] = o;
    }
}

// ---------------- 128x128 GEMM, 2-phase double-buffered ------------------
// The workhorse for ALL GEMMs (R13: 2-phase beat 1-phase; R15/R16: beats
// the 256^2 gemm8p at every shape tried — 5 blocks/CU TLP wins).
// MODE 0: QKV scatter.  MODE 1: bf16 out = acc+bias+res_f32.
// MODE 2: bf16 out = relu(acc+bias).  MODE 3: bf16 out = acc+bias+res_bf16.
template <int MODE>
__global__ __launch_bounds__(256)
void gemm_bt(const u16* __restrict__ A, const u16* __restrict__ Bt,
             const float* __restrict__ bias, const float* __restrict__ res,
             const u16* __restrict__ resb,
             void* __restrict__ outp, int M, int N, int K,
             u16* __restrict__ qb, u16* __restrict__ kb, u16* __restrict__ vT)
{
    __shared__ u16 As[2][128 * 32];
    __shared__ u16 Bs[2][128 * 32];
    const int tid = threadIdx.x;
    const int m0 = blockIdx.x * 128, n0 = blockIdx.y * 128;
    const int wid = tid >> 6, lane = tid & 63;
    const int wm = (wid >> 1) * 64, wn = (wid & 1) * 64;
    const int lr = lane & 15, lg = lane >> 4;
    f32x4 acc[4][4] = {};

    const int row0 = tid >> 2, cc0 = (tid & 3) * 8;
    const int row1 = row0 + 64;
    const int lo0 = (tid & ~63) * 16;
    const int lo1 = 256 * 16 + lo0;

#define GSTG(buf, k0_) do {                                                    \
    __builtin_amdgcn_global_load_lds(                                          \
        AS1(A + (size_t)(m0 + row0) * K + (k0_) + cc0),                        \
        AS3((char*)As[buf] + lo0), 16, 0, 0);                                  \
    __builtin_amdgcn_global_load_lds(                                          \
        AS1(A + (size_t)(m0 + row1) * K + (k0_) + cc0),                        \
        AS3((char*)As[buf] + lo1), 16, 0, 0);                                  \
    __builtin_amdgcn_global_load_lds(                                          \
        AS1(Bt + (size_t)(n0 + row0) * K + (k0_) + cc0),                       \
        AS3((char*)Bs[buf] + lo0), 16, 0, 0);                                  \
    __builtin_amdgcn_global_load_lds(                                          \
        AS1(Bt + (size_t)(n0 + row1) * K + (k0_) + cc0),                       \
        AS3((char*)Bs[buf] + lo1), 16, 0, 0);                                  \
} while (0)

    GSTG(0, 0);
    __syncthreads();

    const int NT = K >> 5;
    for (int t = 0; t < NT; ++t) {
        const int cur = t & 1;
        if (t + 1 < NT) GSTG(cur ^ 1, (t + 1) << 5);
        bf16x8 af[4];
#pragma unroll
        for (int i = 0; i < 4; ++i)
            af[i] = *(const bf16x8*)&As[cur][(wm + i * 16 + lr) * 32 + lg * 8];
#pragma unroll
        for (int j = 0; j < 4; ++j) {
            bf16x8 bf = *(const bf16x8*)&Bs[cur][(wn + j * 16 + lr) * 32 + lg * 8];
#pragma unroll
            for (int i = 0; i < 4; ++i)
                acc[i][j] = __builtin_amdgcn_mfma_f32_16x16x32_bf16(af[i], bf, acc[i][j], 0, 0, 0);
        }
        __syncthreads();
    }
#undef GSTG

#pragma unroll
    for (int i = 0; i < 4; ++i) {
#pragma unroll
        for (int j = 0; j < 4; ++j) {
            int col = n0 + wn + j * 16 + lr;
            float bv = bias[col];
#pragma unroll
            for (int r = 0; r < 4; ++r) {
                int mr = m0 + wm + i * 16 + lg * 4 + r;
                float v = acc[i][j][r] + bv;
                if (MODE == 0) {
                    int b_ = mr >> 11, s_ = mr & 2047;
                    int h_ = col / 192, rr = col - h_ * 192;
                    int bh = b_ * 16 + h_;
                    if (rr < 64)
                        qb[((size_t)bh * 2048 + s_) * 64 + rr] = f2bf(v * (0.125f * LOG2E));
                    else if (rr < 128)
                        kb[((size_t)bh * 2048 + s_) * 64 + (rr - 64)] = f2bf(v);
                    else
                        vT[((size_t)bh * 64 + (rr - 128)) * 2048 + s_] = f2bf(v);
                } else if (MODE == 1) {
                    ((u16*)outp)[(size_t)mr * N + col] = f2bf(v + res[(size_t)mr * N + col]);
                } else if (MODE == 3) {
                    ((u16*)outp)[(size_t)mr * N + col] = f2bf(v + bf2f(resb[(size_t)mr * N + col]));
                } else {
                    ((u16*)outp)[(size_t)mr * N + col] = f2bf(fmaxf(v, 0.0f));
                }
            }
        }
    }
}

// ---------------- flash attention forward (R22) ---------------------------
// R22 = R20 byte-identical per-wave code (mask prefetch + setprio, best
// measured 485.8us total / ~172us attn) with ONE change: the id->job
// mapping. R20 put same-(b,qt) h-blocks 128 ids apart -> the 16 blocks
// reading the SAME 1MB mask slice ran a full dispatch round apart ->
// every one missed L2 (FETCH 329MB vs ~200MB unique). New mapping makes
// the 8 same-(b,qt) sharers on an XCD adjacent in dispatch order
// (ids within a 56 window): first warms L2, rest hit. Same-(b,h)
// K/V qt-sharers stay 8-apart in sequence (L2 reuse preserved).
//   x=id&7 (XCD), s=id>>3: b=x>>1, h=(x&1)*8+(s&7), qt=s>>3. Bijective.
// R21 lesson (revert): register-staging K/V across the iteration spills
// (VGPR 32 + 1GB scratch) — only zero-register-cost edits are admissible.
__global__ __launch_bounds__(512, 8)
void attn_fwd(const u16* __restrict__ qb, const u16* __restrict__ kb,
              const u16* __restrict__ vT, const float* __restrict__ mask,
              u16* __restrict__ ctx)
{
    __shared__ u16 Ks[2][64 * 64];
    __shared__ u16 Vs[2][64 * 64];
    __shared__ u16 Plds[8 * 16 * 68];
    const int tid = threadIdx.x;
    const int wid = tid >> 6, lane = tid & 63;
    const int lr = lane & 15, lg = lane >> 4;
    const int id = blockIdx.x;
    const int x = id & 7, s = id >> 3;
    const int b = x >> 1, h = (x & 1) * 8 + (s & 7), qt = s >> 3;
    const int bh = b * 16 + h;
    const int q0 = qt * 128 + wid * 16;
    u16* pl = &Plds[wid * 16 * 68];

    const size_t kbase = (size_t)bh * 2048 * 64;
    const size_t vbase = (size_t)bh * 64 * 2048;

    const int cr = tid >> 3, ck = tid & 7;
    const int sk = ck ^ (cr & 7);
    const int lo = (tid & ~63) * 16;

    bf16x8 qf[2];
#pragma unroll
    for (int ks = 0; ks < 2; ++ks)
        qf[ks] = *(const bf16x8*)(qb + ((size_t)bh * 2048 + q0 + lr) * 64 + ks * 32 + lg * 8);

    f32x4 octx[4] = {};
    float lsum[4] = {};
    const size_t mbase = ((size_t)b * 2048 + q0) * 2048;

    {
        __builtin_amdgcn_global_load_lds(AS1(kb + kbase + (size_t)cr * 64 + sk * 8),
                                         AS3((char*)Ks[0] + lo), 16, 0, 0);
        __builtin_amdgcn_global_load_lds(AS1(vT + vbase + (size_t)cr * 2048 + sk * 8),
                                         AS3((char*)Vs[0] + lo), 16, 0, 0);
    }

    // mask prefetch for it=0 (loop-carried mv; refilled before each PV)
    float mv[4][4];
#pragma unroll
    for (int j = 0; j < 4; ++j)
#pragma unroll
        for (int r = 0; r < 4; ++r)
            mv[j][r] = mask[mbase + (size_t)(lg * 4 + r) * 2048 + j * 16 + lr];

    for (int it = 0; it < 32; ++it) {
        const int t0 = it * 64;
        const int cur = it & 1;
        __syncthreads();
        if (it < 31) {
            const int tn = t0 + 64;
            __builtin_amdgcn_global_load_lds(AS1(kb + kbase + (size_t)(tn + cr) * 64 + sk * 8),
                                             AS3((char*)Ks[cur ^ 1] + lo), 16, 0, 0);
            __builtin_amdgcn_global_load_lds(AS1(vT + vbase + (size_t)cr * 2048 + tn + sk * 8),
                                             AS3((char*)Vs[cur ^ 1] + lo), 16, 0, 0);
        }

        f32x4 sc[4];
        __builtin_amdgcn_s_setprio(1);
#pragma unroll
        for (int j = 0; j < 4; ++j) {
            f32x4 s2 = {0.f, 0.f, 0.f, 0.f};
#pragma unroll
            for (int ks = 0; ks < 2; ++ks) {
                const int R = j * 16 + lr;
                const int off = R * 128 + ((ks * 64 + lg * 16) ^ ((R & 7) * 16));
                bf16x8 kf = *(const bf16x8*)((const char*)Ks[cur] + off);
                s2 = __builtin_amdgcn_mfma_f32_16x16x32_bf16(qf[ks], kf, s2, 0, 0, 0);
            }
            sc[j] = s2;
        }
        __builtin_amdgcn_s_setprio(0);

#pragma unroll
        for (int j = 0; j < 4; ++j) {
#pragma unroll
            for (int r = 0; r < 4; ++r) {
                float p = __builtin_amdgcn_exp2f(fmaf(mv[j][r], LOG2E, sc[j][r]) - 24.0f);
                sc[j][r] = p;
                lsum[r] += p;
            }
        }
#pragma unroll
        for (int j = 0; j < 4; ++j)
#pragma unroll
            for (int r = 0; r < 4; ++r)
                pl[(lg * 4 + r) * 68 + j * 16 + lr] = f2bf(sc[j][r]);

        // mask prefetch for it+1: covered by PV + barrier + QK before use
        if (it < 31) {
            const int tn = t0 + 64;
#pragma unroll
            for (int j = 0; j < 4; ++j)
#pragma unroll
                for (int r = 0; r < 4; ++r)
                    mv[j][r] = mask[mbase + (size_t)(lg * 4 + r) * 2048 + tn + j * 16 + lr];
        }

        __builtin_amdgcn_s_setprio(1);
#pragma unroll
        for (int ks = 0; ks < 2; ++ks) {
            bf16x8 pa = *(const bf16x8*)&pl[lr * 68 + ks * 32 + lg * 8];
#pragma unroll
            for (int dj = 0; dj < 4; ++dj) {
                const int R = dj * 16 + lr;
                const int off = R * 128 + ((ks * 64 + lg * 16) ^ ((R & 7) * 16));
                bf16x8 vf = *(const bf16x8*)((const char*)Vs[cur] + off);
                octx[dj] = __builtin_amdgcn_mfma_f32_16x16x32_bf16(pa, vf, octx[dj], 0, 0, 0);
            }
        }
        __builtin_amdgcn_s_setprio(0);
    }

#pragma unroll
    for (int r = 0; r < 4; ++r)
#pragma unroll
        for (int o = 1; o < 16; o <<= 1) lsum[r] += __shfl_xor(lsum[r], o);

#pragma unroll
    for (int dj = 0; dj < 4; ++dj)
#pragma unroll
        for (int r = 0; r < 4; ++r) {
            float o = octx[dj][r] / lsum[r];
            ctx[((size_t)b * 2048 + q0 + lg * 4 + r) * 1024 + h * 64 + dj * 16 + lr] = f2bf(o);
        }
}

// ---------------- LayerNorm (row = 1024), bf16 in, eps added to std -------
__global__ __launch_bounds__(256)
void ln_fwd(const u16* __restrict__ in, const float* __restrict__ gamma,
            const float* __restrict__ beta, float* __restrict__ out32,
            u16* __restrict__ outbf)
{
    __shared__ float red[4], red2[4];
    const int tid = threadIdx.x;
    const size_t row = blockIdx.x;
    ushort4 raw = ((const ushort4*)(in + row * 1024))[tid];
    float vx = bf2f(raw.x), vy = bf2f(raw.y), vz = bf2f(raw.z), vw = bf2f(raw.w);
    float s  = vx + vy + vz + vw;
    float s2 = vx * vx + vy * vy + vz * vz + vw * vw;
#pragma unroll
    for (int o = 32; o; o >>= 1) {
        s  += __shfl_xor(s, o);
        s2 += __shfl_xor(s2, o);
    }
    if ((tid & 63) == 0) { red[tid >> 6] = s; red2[tid >> 6] = s2; }
    __syncthreads();
    float mean = (red[0] + red[1] + red[2] + red[3]) * (1.0f / 1024.0f);
    float ex2  = (red2[0] + red2[1] + red2[2] + red2[3]) * (1.0f / 1024.0f);
    float var  = ex2 - mean * mean;
    float inv = 1.0f / (sqrtf(var) + 1e-6f);
    float dx = vx - mean, dy = vy - mean, dz = vz - mean, dw = vw - mean;
    float4 g = ((const float4*)gamma)[tid];
    float4 bb = ((const float4*)beta)[tid];
    float4 o;
    o.x = g.x * dx * inv + bb.x;
    o.y = g.y * dy * inv + bb.y;
    o.z = g.z * dz * inv + bb.z;
    o.w = g.w * dw * inv + bb.w;
    if (out32) ((float4*)(out32 + row * 1024))[tid] = o;
    if (outbf) {
        ushort4 ob;
        ob.x = f2bf(o.x); ob.y = f2bf(o.y); ob.z = f2bf(o.z); ob.w = f2bf(o.w);
        ((ushort4*)(outbf + row * 1024))[tid] = ob;
    }
}

extern "C" void kernel_launch(void* const* d_in, const int* in_sizes, int n_in,
                              void* d_out, int out_size, void* d_ws, size_t ws_size,
                              hipStream_t stream)
{
    (void)in_sizes; (void)n_in; (void)out_size; (void)ws_size;
    const float* x    = (const float*)d_in[0];
    const float* mask = (const float*)d_in[1];
    const float* Wqkv = (const float*)d_in[2];
    const float* bqkv = (const float*)d_in[3];
    const float* Wo   = (const float*)d_in[4];
    const float* bo   = (const float*)d_in[5];
    const float* W1   = (const float*)d_in[6];
    const float* b1   = (const float*)d_in[7];
    const float* W2   = (const float*)d_in[8];
    const float* b2   = (const float*)d_in[9];
    const float* g1   = (const float*)d_in[10];
    const float* be1  = (const float*)d_in[11];
    const float* g2   = (const float*)d_in[12];
    const float* be2  = (const float*)d_in[13];

    char* w = (char*)d_ws;
    u16* x_bf    = (u16*)w;  w += (size_t)8192 * 1024 * 2;   // kept live (Wo residual)
    u16* Wqkv_bf = (u16*)w;  w += (size_t)3072 * 1024 * 2;
    u16* Wo_bf   = (u16*)w;  w += (size_t)1024 * 1024 * 2;
    u16* W1_bf   = (u16*)w;  w += (size_t)4096 * 1024 * 2;
    u16* W2_bf   = (u16*)w;  w += (size_t)1024 * 4096 * 2;
    u16* qbuf    = (u16*)w;  w += (size_t)8192 * 1024 * 2;
    u16* kbuf    = (u16*)w;  w += (size_t)8192 * 1024 * 2;
    u16* vTbuf   = (u16*)w;  w += (size_t)8192 * 1024 * 2;
    u16* ctxbuf  = (u16*)w;  w += (size_t)8192 * 1024 * 2;
    u16* hb_wo   = (u16*)w;  w += (size_t)8192 * 1024 * 2;   // Wo out -> ln1 in
    u16* hbf     = (u16*)w;  w += (size_t)8192 * 1024 * 2;   // ln1 out: W1 A + W2 residual
    u16* hb_w2   = (u16*)w;  w += (size_t)8192 * 1024 * 2;   // W2 out -> ln2 in
    u16* ff1     = (u16*)w;  w += (size_t)8192 * 4096 * 2;

    cast_all_bf16<<<2048, 256, 0, stream>>>(x, Wqkv, Wo, W1, W2,
                                            x_bf, Wqkv_bf, Wo_bf, W1_bf, W2_bf);

    gemm_bt<0><<<dim3(64, 24), 256, 0, stream>>>(x_bf, Wqkv_bf, bqkv, nullptr, nullptr, nullptr,
                                                 8192, 3072, 1024, qbuf, kbuf, vTbuf);
    attn_fwd<<<1024, 512, 0, stream>>>(qbuf, kbuf, vTbuf, mask, ctxbuf);
    gemm_bt<3><<<dim3(64, 8), 256, 0, stream>>>(ctxbuf, Wo_bf, bo, nullptr, x_bf, hb_wo,
                                                8192, 1024, 1024, nullptr, nullptr, nullptr);
    ln_fwd<<<8192, 256, 0, stream>>>(hb_wo, g1, be1, nullptr, hbf);
    gemm_bt<2><<<dim3(64, 32), 256, 0, stream>>>(hbf, W1_bf, b1, nullptr, nullptr, ff1,
                                                 8192, 4096, 1024, nullptr, nullptr, nullptr);
    gemm_bt<3><<<dim3(64, 8), 256, 0, stream>>>(ff1, W2_bf, b2, nullptr, hbf, hb_w2,
                                                8192, 1024, 4096, nullptr, nullptr, nullptr);
    ln_fwd<<<8192, 256, 0, stream>>>(hb_w2, g2, be2, (float*)d_out, nullptr);
}

// Round 7
// 484.386 us; speedup vs baseline: 1.8907x; 1.0120x over previous
//
#include <hip/hip_runtime.h>

typedef unsigned short u16;
typedef float f32x4 __attribute__((ext_vector_type(4)));
typedef __bf16 bf16x8 __attribute__((ext_vector_type(8)));

#define AS1(p) ((const __attribute__((address_space(1))) void*)(p))
#define AS3(p) ((__attribute__((address_space(3))) void*)(p))

#define LOG2E 1.44269504088896f

__device__ __forceinline__ u16 f2bf(float f) {
    return __builtin_bit_cast(u16, (__bf16)f);   // RTNE, hw cvt on gfx950
}
__device__ __forceinline__ float bf2f(u16 u) {
    return __builtin_bit_cast(float, (unsigned)u << 16);
}

// ---------------- fused cast f32 -> bf16 over 5 segments ----------------
__global__ __launch_bounds__(256) void cast_all_bf16(
    const float* __restrict__ s0, const float* __restrict__ s1,
    const float* __restrict__ s2, const float* __restrict__ s3,
    const float* __restrict__ s4,
    u16* __restrict__ d0, u16* __restrict__ d1, u16* __restrict__ d2,
    u16* __restrict__ d3, u16* __restrict__ d4)
{
    const int n0 = 2097152;
    const int e1 = n0 + 786432;
    const int e2 = e1 + 262144;
    const int e3 = e2 + 1048576;
    const int e4 = e3 + 1048576;
    int stride = gridDim.x * blockDim.x;
    for (int i = blockIdx.x * blockDim.x + threadIdx.x; i < e4; i += stride) {
        const float* src; u16* dst; int li;
        if (i < n0)      { src = s0; dst = d0; li = i; }
        else if (i < e1) { src = s1; dst = d1; li = i - n0; }
        else if (i < e2) { src = s2; dst = d2; li = i - e1; }
        else if (i < e3) { src = s3; dst = d3; li = i - e2; }
        else             { src = s4; dst = d4; li = i - e3; }
        float4 v = ((const float4*)src)[li];
        ushort4 o;
        o.x = f2bf(v.x); o.y = f2bf(v.y); o.z = f2bf(v.z); o.w = f2bf(v.w);
        ((ushort4*)dst)[li] = o;
    }
}

// ---------------- 128x128 GEMM, 2-phase double-buffered ------------------
// The workhorse for ALL GEMMs (R13: 2-phase beat 1-phase; R15/R16: beats
// the 256^2 gemm8p at every shape tried — 5 blocks/CU TLP wins).
// MODE 0: QKV scatter.  MODE 1: bf16 out = acc+bias+res_f32.
// MODE 2: bf16 out = relu(acc+bias).  MODE 3: bf16 out = acc+bias+res_bf16.
template <int MODE>
__global__ __launch_bounds__(256)
void gemm_bt(const u16* __restrict__ A, const u16* __restrict__ Bt,
             const float* __restrict__ bias, const float* __restrict__ res,
             const u16* __restrict__ resb,
             void* __restrict__ outp, int M, int N, int K,
             u16* __restrict__ qb, u16* __restrict__ kb, u16* __restrict__ vT)
{
    __shared__ u16 As[2][128 * 32];
    __shared__ u16 Bs[2][128 * 32];
    const int tid = threadIdx.x;
    const int m0 = blockIdx.x * 128, n0 = blockIdx.y * 128;
    const int wid = tid >> 6, lane = tid & 63;
    const int wm = (wid >> 1) * 64, wn = (wid & 1) * 64;
    const int lr = lane & 15, lg = lane >> 4;
    f32x4 acc[4][4] = {};

    const int row0 = tid >> 2, cc0 = (tid & 3) * 8;
    const int row1 = row0 + 64;
    const int lo0 = (tid & ~63) * 16;
    const int lo1 = 256 * 16 + lo0;

#define GSTG(buf, k0_) do {                                                    \
    __builtin_amdgcn_global_load_lds(                                          \
        AS1(A + (size_t)(m0 + row0) * K + (k0_) + cc0),                        \
        AS3((char*)As[buf] + lo0), 16, 0, 0);                                  \
    __builtin_amdgcn_global_load_lds(                                          \
        AS1(A + (size_t)(m0 + row1) * K + (k0_) + cc0),                        \
        AS3((char*)As[buf] + lo1), 16, 0, 0);                                  \
    __builtin_amdgcn_global_load_lds(                                          \
        AS1(Bt + (size_t)(n0 + row0) * K + (k0_) + cc0),                       \
        AS3((char*)Bs[buf] + lo0), 16, 0, 0);                                  \
    __builtin_amdgcn_global_load_lds(                                          \
        AS1(Bt + (size_t)(n0 + row1) * K + (k0_) + cc0),                       \
        AS3((char*)Bs[buf] + lo1), 16, 0, 0);                                  \
} while (0)

    GSTG(0, 0);
    __syncthreads();

    const int NT = K >> 5;
    for (int t = 0; t < NT; ++t) {
        const int cur = t & 1;
        if (t + 1 < NT) GSTG(cur ^ 1, (t + 1) << 5);
        bf16x8 af[4];
#pragma unroll
        for (int i = 0; i < 4; ++i)
            af[i] = *(const bf16x8*)&As[cur][(wm + i * 16 + lr) * 32 + lg * 8];
#pragma unroll
        for (int j = 0; j < 4; ++j) {
            bf16x8 bf = *(const bf16x8*)&Bs[cur][(wn + j * 16 + lr) * 32 + lg * 8];
#pragma unroll
            for (int i = 0; i < 4; ++i)
                acc[i][j] = __builtin_amdgcn_mfma_f32_16x16x32_bf16(af[i], bf, acc[i][j], 0, 0, 0);
        }
        __syncthreads();
    }
#undef GSTG

#pragma unroll
    for (int i = 0; i < 4; ++i) {
#pragma unroll
        for (int j = 0; j < 4; ++j) {
            int col = n0 + wn + j * 16 + lr;
            float bv = bias[col];
#pragma unroll
            for (int r = 0; r < 4; ++r) {
                int mr = m0 + wm + i * 16 + lg * 4 + r;
                float v = acc[i][j][r] + bv;
                if (MODE == 0) {
                    int b_ = mr >> 11, s_ = mr & 2047;
                    int h_ = col / 192, rr = col - h_ * 192;
                    int bh = b_ * 16 + h_;
                    if (rr < 64)
                        qb[((size_t)bh * 2048 + s_) * 64 + rr] = f2bf(v * (0.125f * LOG2E));
                    else if (rr < 128)
                        kb[((size_t)bh * 2048 + s_) * 64 + (rr - 64)] = f2bf(v);
                    else
                        vT[((size_t)bh * 64 + (rr - 128)) * 2048 + s_] = f2bf(v);
                } else if (MODE == 1) {
                    ((u16*)outp)[(size_t)mr * N + col] = f2bf(v + res[(size_t)mr * N + col]);
                } else if (MODE == 3) {
                    ((u16*)outp)[(size_t)mr * N + col] = f2bf(v + bf2f(resb[(size_t)mr * N + col]));
                } else {
                    ((u16*)outp)[(size_t)mr * N + col] = f2bf(fmaxf(v, 0.0f));
                }
            }
        }
    }
}

// ---------------- flash attention forward (R20 FINAL) ---------------------
// R20 = R10 structure (1024 blocks x 512 thr, KVBLK=64 dbuf, Plds 68-pad,
// static-C softmax, XCD swizzle) + mask software-pipelining (it+1 loads
// issued before PV of it) + T5 setprio around MFMA clusters. Best measured:
// 485.8us total / ~172us attn.
// Session evidence (R17-R22): every structural change lost —
//   R17 in-reg P repack: serial permlane chain on critical path (222us)
//   R18 16-wave block: spill at 64-VGPR cap (267us)
//   R19 2 q-tiles/wave: spill (349us)
//   R21 single-buf reg staging: spill, 1GB scratch (564us)
//   R22 L2-sharing dispatch order: FETCH -65% but dur +5% (latency-hidden)
// Residency pinned at 3 blocks/CU by 50KB LDS; register envelope pinned
// by the 64-VGPR occupancy cliff. Only zero-register scheduling edits won.
__global__ __launch_bounds__(512, 8)
void attn_fwd(const u16* __restrict__ qb, const u16* __restrict__ kb,
              const u16* __restrict__ vT, const float* __restrict__ mask,
              u16* __restrict__ ctx)
{
    __shared__ u16 Ks[2][64 * 64];
    __shared__ u16 Vs[2][64 * 64];
    __shared__ u16 Plds[8 * 16 * 68];
    const int tid = threadIdx.x;
    const int wid = tid >> 6, lane = tid & 63;
    const int lr = lane & 15, lg = lane >> 4;
    const int id = blockIdx.x;
    const int job = (id & 7) * 128 + (id >> 3);
    const int qt = job & 15, h = (job >> 4) & 15, b = job >> 8;
    const int bh = b * 16 + h;
    const int q0 = qt * 128 + wid * 16;
    u16* pl = &Plds[wid * 16 * 68];

    const size_t kbase = (size_t)bh * 2048 * 64;
    const size_t vbase = (size_t)bh * 64 * 2048;

    const int cr = tid >> 3, ck = tid & 7;
    const int sk = ck ^ (cr & 7);
    const int lo = (tid & ~63) * 16;

    bf16x8 qf[2];
#pragma unroll
    for (int ks = 0; ks < 2; ++ks)
        qf[ks] = *(const bf16x8*)(qb + ((size_t)bh * 2048 + q0 + lr) * 64 + ks * 32 + lg * 8);

    f32x4 octx[4] = {};
    float lsum[4] = {};
    const size_t mbase = ((size_t)b * 2048 + q0) * 2048;

    {
        __builtin_amdgcn_global_load_lds(AS1(kb + kbase + (size_t)cr * 64 + sk * 8),
                                         AS3((char*)Ks[0] + lo), 16, 0, 0);
        __builtin_amdgcn_global_load_lds(AS1(vT + vbase + (size_t)cr * 2048 + sk * 8),
                                         AS3((char*)Vs[0] + lo), 16, 0, 0);
    }

    // mask prefetch for it=0 (loop-carried mv; refilled before each PV)
    float mv[4][4];
#pragma unroll
    for (int j = 0; j < 4; ++j)
#pragma unroll
        for (int r = 0; r < 4; ++r)
            mv[j][r] = mask[mbase + (size_t)(lg * 4 + r) * 2048 + j * 16 + lr];

    for (int it = 0; it < 32; ++it) {
        const int t0 = it * 64;
        const int cur = it & 1;
        __syncthreads();
        if (it < 31) {
            const int tn = t0 + 64;
            __builtin_amdgcn_global_load_lds(AS1(kb + kbase + (size_t)(tn + cr) * 64 + sk * 8),
                                             AS3((char*)Ks[cur ^ 1] + lo), 16, 0, 0);
            __builtin_amdgcn_global_load_lds(AS1(vT + vbase + (size_t)cr * 2048 + tn + sk * 8),
                                             AS3((char*)Vs[cur ^ 1] + lo), 16, 0, 0);
        }

        f32x4 sc[4];
        __builtin_amdgcn_s_setprio(1);
#pragma unroll
        for (int j = 0; j < 4; ++j) {
            f32x4 s = {0.f, 0.f, 0.f, 0.f};
#pragma unroll
            for (int ks = 0; ks < 2; ++ks) {
                const int R = j * 16 + lr;
                const int off = R * 128 + ((ks * 64 + lg * 16) ^ ((R & 7) * 16));
                bf16x8 kf = *(const bf16x8*)((const char*)Ks[cur] + off);
                s = __builtin_amdgcn_mfma_f32_16x16x32_bf16(qf[ks], kf, s, 0, 0, 0);
            }
            sc[j] = s;
        }
        __builtin_amdgcn_s_setprio(0);

#pragma unroll
        for (int j = 0; j < 4; ++j) {
#pragma unroll
            for (int r = 0; r < 4; ++r) {
                float p = __builtin_amdgcn_exp2f(fmaf(mv[j][r], LOG2E, sc[j][r]) - 24.0f);
                sc[j][r] = p;
                lsum[r] += p;
            }
        }
#pragma unroll
        for (int j = 0; j < 4; ++j)
#pragma unroll
            for (int r = 0; r < 4; ++r)
                pl[(lg * 4 + r) * 68 + j * 16 + lr] = f2bf(sc[j][r]);

        // mask prefetch for it+1: covered by PV + barrier + QK before use
        if (it < 31) {
            const int tn = t0 + 64;
#pragma unroll
            for (int j = 0; j < 4; ++j)
#pragma unroll
                for (int r = 0; r < 4; ++r)
                    mv[j][r] = mask[mbase + (size_t)(lg * 4 + r) * 2048 + tn + j * 16 + lr];
        }

        __builtin_amdgcn_s_setprio(1);
#pragma unroll
        for (int ks = 0; ks < 2; ++ks) {
            bf16x8 pa = *(const bf16x8*)&pl[lr * 68 + ks * 32 + lg * 8];
#pragma unroll
            for (int dj = 0; dj < 4; ++dj) {
                const int R = dj * 16 + lr;
                const int off = R * 128 + ((ks * 64 + lg * 16) ^ ((R & 7) * 16));
                bf16x8 vf = *(const bf16x8*)((const char*)Vs[cur] + off);
                octx[dj] = __builtin_amdgcn_mfma_f32_16x16x32_bf16(pa, vf, octx[dj], 0, 0, 0);
            }
        }
        __builtin_amdgcn_s_setprio(0);
    }

#pragma unroll
    for (int r = 0; r < 4; ++r)
#pragma unroll
        for (int o = 1; o < 16; o <<= 1) lsum[r] += __shfl_xor(lsum[r], o);

#pragma unroll
    for (int dj = 0; dj < 4; ++dj)
#pragma unroll
        for (int r = 0; r < 4; ++r) {
            float o = octx[dj][r] / lsum[r];
            ctx[((size_t)b * 2048 + q0 + lg * 4 + r) * 1024 + h * 64 + dj * 16 + lr] = f2bf(o);
        }
}

// ---------------- LayerNorm (row = 1024), bf16 in, eps added to std -------
__global__ __launch_bounds__(256)
void ln_fwd(const u16* __restrict__ in, const float* __restrict__ gamma,
            const float* __restrict__ beta, float* __restrict__ out32,
            u16* __restrict__ outbf)
{
    __shared__ float red[4], red2[4];
    const int tid = threadIdx.x;
    const size_t row = blockIdx.x;
    ushort4 raw = ((const ushort4*)(in + row * 1024))[tid];
    float vx = bf2f(raw.x), vy = bf2f(raw.y), vz = bf2f(raw.z), vw = bf2f(raw.w);
    float s  = vx + vy + vz + vw;
    float s2 = vx * vx + vy * vy + vz * vz + vw * vw;
#pragma unroll
    for (int o = 32; o; o >>= 1) {
        s  += __shfl_xor(s, o);
        s2 += __shfl_xor(s2, o);
    }
    if ((tid & 63) == 0) { red[tid >> 6] = s; red2[tid >> 6] = s2; }
    __syncthreads();
    float mean = (red[0] + red[1] + red[2] + red[3]) * (1.0f / 1024.0f);
    float ex2  = (red2[0] + red2[1] + red2[2] + red2[3]) * (1.0f / 1024.0f);
    float var  = ex2 - mean * mean;
    float inv = 1.0f / (sqrtf(var) + 1e-6f);
    float dx = vx - mean, dy = vy - mean, dz = vz - mean, dw = vw - mean;
    float4 g = ((const float4*)gamma)[tid];
    float4 bb = ((const float4*)beta)[tid];
    float4 o;
    o.x = g.x * dx * inv + bb.x;
    o.y = g.y * dy * inv + bb.y;
    o.z = g.z * dz * inv + bb.z;
    o.w = g.w * dw * inv + bb.w;
    if (out32) ((float4*)(out32 + row * 1024))[tid] = o;
    if (outbf) {
        ushort4 ob;
        ob.x = f2bf(o.x); ob.y = f2bf(o.y); ob.z = f2bf(o.z); ob.w = f2bf(o.w);
        ((ushort4*)(outbf + row * 1024))[tid] = ob;
    }
}

extern "C" void kernel_launch(void* const* d_in, const int* in_sizes, int n_in,
                              void* d_out, int out_size, void* d_ws, size_t ws_size,
                              hipStream_t stream)
{
    (void)in_sizes; (void)n_in; (void)out_size; (void)ws_size;
    const float* x    = (const float*)d_in[0];
    const float* mask = (const float*)d_in[1];
    const float* Wqkv = (const float*)d_in[2];
    const float* bqkv = (const float*)d_in[3];
    const float* Wo   = (const float*)d_in[4];
    const float* bo   = (const float*)d_in[5];
    const float* W1   = (const float*)d_in[6];
    const float* b1   = (const float*)d_in[7];
    const float* W2   = (const float*)d_in[8];
    const float* b2   = (const float*)d_in[9];
    const float* g1   = (const float*)d_in[10];
    const float* be1  = (const float*)d_in[11];
    const float* g2   = (const float*)d_in[12];
    const float* be2  = (const float*)d_in[13];

    char* w = (char*)d_ws;
    u16* x_bf    = (u16*)w;  w += (size_t)8192 * 1024 * 2;   // kept live (Wo residual)
    u16* Wqkv_bf = (u16*)w;  w += (size_t)3072 * 1024 * 2;
    u16* Wo_bf   = (u16*)w;  w += (size_t)1024 * 1024 * 2;
    u16* W1_bf   = (u16*)w;  w += (size_t)4096 * 1024 * 2;
    u16* W2_bf   = (u16*)w;  w += (size_t)1024 * 4096 * 2;
    u16* qbuf    = (u16*)w;  w += (size_t)8192 * 1024 * 2;
    u16* kbuf    = (u16*)w;  w += (size_t)8192 * 1024 * 2;
    u16* vTbuf   = (u16*)w;  w += (size_t)8192 * 1024 * 2;
    u16* ctxbuf  = (u16*)w;  w += (size_t)8192 * 1024 * 2;
    u16* hb_wo   = (u16*)w;  w += (size_t)8192 * 1024 * 2;   // Wo out -> ln1 in
    u16* hbf     = (u16*)w;  w += (size_t)8192 * 1024 * 2;   // ln1 out: W1 A + W2 residual
    u16* hb_w2   = (u16*)w;  w += (size_t)8192 * 1024 * 2;   // W2 out -> ln2 in
    u16* ff1     = (u16*)w;  w += (size_t)8192 * 4096 * 2;

    cast_all_bf16<<<2048, 256, 0, stream>>>(x, Wqkv, Wo, W1, W2,
                                            x_bf, Wqkv_bf, Wo_bf, W1_bf, W2_bf);

    gemm_bt<0><<<dim3(64, 24), 256, 0, stream>>>(x_bf, Wqkv_bf, bqkv, nullptr, nullptr, nullptr,
                                                 8192, 3072, 1024, qbuf, kbuf, vTbuf);
    attn_fwd<<<1024, 512, 0, stream>>>(qbuf, kbuf, vTbuf, mask, ctxbuf);
    gemm_bt<3><<<dim3(64, 8), 256, 0, stream>>>(ctxbuf, Wo_bf, bo, nullptr, x_bf, hb_wo,
                                                8192, 1024, 1024, nullptr, nullptr, nullptr);
    ln_fwd<<<8192, 256, 0, stream>>>(hb_wo, g1, be1, nullptr, hbf);
    gemm_bt<2><<<dim3(64, 32), 256, 0, stream>>>(hbf, W1_bf, b1, nullptr, nullptr, ff1,
                                                 8192, 4096, 1024, nullptr, nullptr, nullptr);
    gemm_bt<3><<<dim3(64, 8), 256, 0, stream>>>(ff1, W2_bf, b2, nullptr, hbf, hb_w2,
                                                8192, 1024, 4096, nullptr, nullptr, nullptr);
    ln_fwd<<<8192, 256, 0, stream>>>(hb_w2, g2, be2, (float*)d_out, nullptr);
}